// Round 2
// baseline (31539.355 us; speedup 1.0000x reference)
//
#include <hip/hip_runtime.h>

#define BB 64
#define TT 1024
#define DD 512
#define BT (BB*TT)

typedef float f4 __attribute__((ext_vector_type(4)));

// ===========================================================================
// GEMM: C[bt, e'] = sum_d x[bt,d] * W[e',d] + bias[e']   (all f32)
// (unchanged — verified absmax 0.0)
// ===========================================================================
__global__ __launch_bounds__(256, 2) void gemm_kernel(
    const float* __restrict__ x, const float* __restrict__ tau_w,
    const float* __restrict__ tau_b, const float* __restrict__ mem_w,
    const float* __restrict__ mem_b, float* __restrict__ xp, float* __restrict__ mm)
{
    __shared__ float As[32][132];
    __shared__ float Bs[32][68];

    const int tid  = threadIdx.x;
    const int bt0  = blockIdx.x * 128;
    const bool isxp = (blockIdx.y < 8);
    const float* W       = isxp ? tau_w : mem_w;
    const int    wstride = isxp ? 1024 : 512;
    const int    e0      = isxp ? blockIdx.y * 64 : blockIdx.y * 64 - 512;
    const float* bias    = isxp ? tau_b : mem_b;
    float*       dst     = isxp ? xp : mm;

    const int tm = tid & 31, tn = tid >> 5;
    const int lr = tid >> 3, lc = tid & 7;

    float bias_r[8];
#pragma unroll
    for (int ni = 0; ni < 8; ni++) bias_r[ni] = bias[e0 + tn * 8 + ni];

    float acc[4][8] = {};
    float4 pa[4], pb[2];

#pragma unroll
    for (int j = 0; j < 4; j++)
        pa[j] = *(const float4*)(x + (size_t)(bt0 + lr + 32 * j) * DD + lc * 4);
#pragma unroll
    for (int j = 0; j < 2; j++)
        pb[j] = *(const float4*)(W + (size_t)(e0 + lr + 32 * j) * wstride + lc * 4);

    for (int kb = 0; kb < DD; kb += 32) {
#pragma unroll
        for (int j = 0; j < 4; j++) {
            As[lc * 4 + 0][lr + 32 * j] = pa[j].x;
            As[lc * 4 + 1][lr + 32 * j] = pa[j].y;
            As[lc * 4 + 2][lr + 32 * j] = pa[j].z;
            As[lc * 4 + 3][lr + 32 * j] = pa[j].w;
        }
#pragma unroll
        for (int j = 0; j < 2; j++) {
            Bs[lc * 4 + 0][lr + 32 * j] = pb[j].x;
            Bs[lc * 4 + 1][lr + 32 * j] = pb[j].y;
            Bs[lc * 4 + 2][lr + 32 * j] = pb[j].z;
            Bs[lc * 4 + 3][lr + 32 * j] = pb[j].w;
        }
        __syncthreads();
        if (kb + 32 < DD) {
#pragma unroll
            for (int j = 0; j < 4; j++)
                pa[j] = *(const float4*)(x + (size_t)(bt0 + lr + 32 * j) * DD + kb + 32 + lc * 4);
#pragma unroll
            for (int j = 0; j < 2; j++)
                pb[j] = *(const float4*)(W + (size_t)(e0 + lr + 32 * j) * wstride + kb + 32 + lc * 4);
        }
#pragma unroll
        for (int k = 0; k < 32; k++) {
            float4 av  = *(const float4*)&As[k][tm * 4];
            float4 bv0 = *(const float4*)&Bs[k][tn * 8];
            float4 bv1 = *(const float4*)&Bs[k][tn * 8 + 4];
            float a_[4] = {av.x, av.y, av.z, av.w};
            float b_[8] = {bv0.x, bv0.y, bv0.z, bv0.w, bv1.x, bv1.y, bv1.z, bv1.w};
#pragma unroll
            for (int mi = 0; mi < 4; mi++)
#pragma unroll
                for (int ni = 0; ni < 8; ni++)
                    acc[mi][ni] = fmaf(a_[mi], b_[ni], acc[mi][ni]);
        }
        __syncthreads();
    }

#pragma unroll
    for (int mi = 0; mi < 4; mi++) {
        const int row = bt0 + tm * 4 + mi;
        float o[8];
#pragma unroll
        for (int ni = 0; ni < 8; ni++) o[ni] = __fadd_rn(acc[mi][ni], bias_r[ni]);
        float4 s0 = {o[0], o[1], o[2], o[3]};
        float4 s1 = {o[4], o[5], o[6], o[7]};
        *(float4*)(dst + (size_t)row * DD + e0 + tn * 8)     = s0;
        *(float4*)(dst + (size_t)row * DD + e0 + tn * 8 + 4) = s1;
    }
}

// ===========================================================================
// Scan: ONE 1024-thread WG per batch (64 WGs). No cross-WG communication.
// Thread (h = tid>>9, e = tid&511) holds Wt[e, h*256 .. h*256+255]:
//   chunk 2h   (128 f32) pinned to arch VGPRs  ("v" constraint)
//   chunk 2h+1 (128 f32) pinned to AGPRs       ("a" constraint)
// gfx950 unified RF: 256 arch-VGPR + 256 AGPR per wave; at 4 waves/SIMD the
// 2048-reg file allows 512/wave, but the "v" encoding caps at 256 — round-1
// pinned 256 values "v" and the allocator spilled ALL of them to scratch
// (VGPR_Count=64, FETCH 20 GB). Splitting v/a keeps both halves resident;
// CDNA VALU sources AGPRs directly (worst case: accvgpr_read copies).
// Reduction tree replicates the verified kernel bit-for-bit:
// per-chunk (a0+a1)+(a2+a3), total (P0+P1)+(P2+P3).
// ===========================================================================
__global__ __launch_bounds__(1024, 1) void scan_kernel(
    const float* __restrict__ tau_w,
    float* __restrict__ xp_sp,          // out base: xp in, spikes out (in-place)
    const float* __restrict__ mm,       // ws: m (B,T,D)
    const float* __restrict__ thrp,
    float* __restrict__ tau_out, float* __restrict__ v_out)
{
    __shared__ __align__(16) float tau_lds[DD];
    __shared__ float partial[DD];

    const int b   = blockIdx.x;
    const int tid = threadIdx.x;
    const int h   = tid >> 9;        // 0: chunks 0,1 (k 0..255); 1: chunks 2,3
    const int e   = tid & 511;
    const bool owner = (h == 0);     // waves 0..7

    // resident weights: chunk c0 = 2h -> VGPRs, chunk c1 = 2h+1 -> AGPRs
    float wv[128];   // Wt[e][(2h)*128 + k],   k = 0..127
    float wa[128];   // Wt[e][(2h+1)*128 + k], k = 0..127
    {
        const f4* r0 = (const f4*)(tau_w + (size_t)e * 1024 + 512 + (2 * h) * 128);
        const f4* r1 = (const f4*)(tau_w + (size_t)e * 1024 + 512 + (2 * h + 1) * 128);
#pragma unroll
        for (int j = 0; j < 32; j++) {
            f4 t = r0[j];
            wv[4 * j + 0] = t.x; wv[4 * j + 1] = t.y;
            wv[4 * j + 2] = t.z; wv[4 * j + 3] = t.w;
        }
#pragma unroll
        for (int j = 0; j < 32; j++) {
            f4 t = r1[j];
            wa[4 * j + 0] = t.x; wa[4 * j + 1] = t.y;
            wa[4 * j + 2] = t.z; wa[4 * j + 3] = t.w;
        }
    }
#pragma unroll
    for (int j = 0; j < 128; j++) asm volatile("" : "+v"(wv[j]));  // arch VGPR
#pragma unroll
    for (int j = 0; j < 128; j++) asm volatile("" : "+a"(wa[j]));  // AGPR

    if (tid < DD) tau_lds[tid] = 1.0f;

    const float thr = thrp[0];
    float v = 0.0f, tau_keep = 1.0f;
    const size_t baseio = (size_t)b * TT * DD + e;

    __syncthreads();

    for (int i = 0; i < TT; i++) {
        // prefetch step inputs (in flight during the dot)
        float xpv = 0.0f, mv = 0.0f;
        if (owner) {
            xpv = xp_sp[baseio + (size_t)i * DD];
            mv  = mm  [baseio + (size_t)i * DD];
        }

        // dot over this thread's 2 chunks; tau reads are wave-uniform ->
        // LDS broadcast, conflict-free.
        float q;
        {
            float p0, p1;
            {   // chunk 2h (VGPR weights)
                const f4* tl = (const f4*)&tau_lds[(2 * h) * 128];
                float a0 = 0.f, a1 = 0.f, a2 = 0.f, a3 = 0.f;
#pragma unroll
                for (int j = 0; j < 32; j++) {
                    f4 t4 = tl[j];
                    a0 = fmaf(wv[4 * j + 0], t4.x, a0);
                    a1 = fmaf(wv[4 * j + 1], t4.y, a1);
                    a2 = fmaf(wv[4 * j + 2], t4.z, a2);
                    a3 = fmaf(wv[4 * j + 3], t4.w, a3);
                }
                p0 = (a0 + a1) + (a2 + a3);
            }
            {   // chunk 2h+1 (AGPR weights)
                const f4* tl = (const f4*)&tau_lds[(2 * h + 1) * 128];
                float a0 = 0.f, a1 = 0.f, a2 = 0.f, a3 = 0.f;
#pragma unroll
                for (int j = 0; j < 32; j++) {
                    f4 t4 = tl[j];
                    a0 = fmaf(wa[4 * j + 0], t4.x, a0);
                    a1 = fmaf(wa[4 * j + 1], t4.y, a1);
                    a2 = fmaf(wa[4 * j + 2], t4.z, a2);
                    a3 = fmaf(wa[4 * j + 3], t4.w, a3);
                }
                p1 = (a0 + a1) + (a2 + a3);
            }
            q = p0 + p1;   // h=0: P0+P1 ; h=1: P2+P3
        }
        if (!owner) partial[e] = q;
        __syncthreads();   // B: partials visible; all tau reads of step i done

        float tau_n = 0.0f;
        if (owner) {
            float dotv = q + partial[e];          // (P0+P1)+(P2+P3) — exact tree
            float z    = __fadd_rn(xpv, dotv);
            float enz  = expf(-z);
            tau_n      = 1.0f / __fadd_rn(1.0f, enz);
            tau_lds[e] = tau_n;                   // publish FIRST
        }
        __syncthreads();   // A: tau for step i+1 visible

        // tail overlaps next step's dot (non-owner waves already computing)
        if (owner) {
            tau_keep    = tau_n;
            float tpe   = __fadd_rn(tau_n, 1e-6f);
            float alpha = expf(-1.0f / tpe);
            float vn = __fadd_rn(__fmul_rn(alpha, v),
                                 __fmul_rn(__fsub_rn(1.0f, alpha), mv));
            bool s = (vn >= thr);
            xp_sp[baseio + (size_t)i * DD] = s ? 1.0f : 0.0f;
            v = s ? 0.0f : vn;
        }
    }

    if (owner) {
        tau_out[b * DD + e] = tau_keep;
        v_out  [b * DD + e] = v;
    }
}

extern "C" void kernel_launch(void* const* d_in, const int* in_sizes, int n_in,
                              void* d_out, int out_size, void* d_ws, size_t ws_size,
                              hipStream_t stream) {
    (void)in_sizes; (void)n_in; (void)out_size; (void)ws_size;
    const float* x     = (const float*)d_in[0];
    const float* tau_w = (const float*)d_in[1];
    const float* tau_b = (const float*)d_in[2];
    const float* mem_w = (const float*)d_in[3];
    const float* mem_b = (const float*)d_in[4];
    const float* thr   = (const float*)d_in[5];
    float* out = (float*)d_out;

    float* mm = (float*)d_ws;

    gemm_kernel<<<dim3(512, 16), 256, 0, stream>>>(x, tau_w, tau_b, mem_w, mem_b,
                                                   out, mm);
    scan_kernel<<<64, 1024, 0, stream>>>(tau_w, out, mm, thr,
                                         out + (size_t)BT * DD,
                                         out + (size_t)BT * DD + (size_t)BB * DD);
}

// Round 3
// 31530.399 us; speedup vs baseline: 1.0003x; 1.0003x over previous
//
#include <hip/hip_runtime.h>

#define BB 64
#define TT 1024
#define DD 512
#define BT (BB*TT)

typedef float f4 __attribute__((ext_vector_type(4)));

// ===========================================================================
// GEMM: C[bt, e'] = sum_d x[bt,d] * W[e',d] + bias[e']   (all f32)
// (unchanged — verified absmax 0.0)
// ===========================================================================
__global__ __launch_bounds__(256, 2) void gemm_kernel(
    const float* __restrict__ x, const float* __restrict__ tau_w,
    const float* __restrict__ tau_b, const float* __restrict__ mem_w,
    const float* __restrict__ mem_b, float* __restrict__ xp, float* __restrict__ mm)
{
    __shared__ float As[32][132];
    __shared__ float Bs[32][68];

    const int tid  = threadIdx.x;
    const int bt0  = blockIdx.x * 128;
    const bool isxp = (blockIdx.y < 8);
    const float* W       = isxp ? tau_w : mem_w;
    const int    wstride = isxp ? 1024 : 512;
    const int    e0      = isxp ? blockIdx.y * 64 : blockIdx.y * 64 - 512;
    const float* bias    = isxp ? tau_b : mem_b;
    float*       dst     = isxp ? xp : mm;

    const int tm = tid & 31, tn = tid >> 5;
    const int lr = tid >> 3, lc = tid & 7;

    float bias_r[8];
#pragma unroll
    for (int ni = 0; ni < 8; ni++) bias_r[ni] = bias[e0 + tn * 8 + ni];

    float acc[4][8] = {};
    float4 pa[4], pb[2];

#pragma unroll
    for (int j = 0; j < 4; j++)
        pa[j] = *(const float4*)(x + (size_t)(bt0 + lr + 32 * j) * DD + lc * 4);
#pragma unroll
    for (int j = 0; j < 2; j++)
        pb[j] = *(const float4*)(W + (size_t)(e0 + lr + 32 * j) * wstride + lc * 4);

    for (int kb = 0; kb < DD; kb += 32) {
#pragma unroll
        for (int j = 0; j < 4; j++) {
            As[lc * 4 + 0][lr + 32 * j] = pa[j].x;
            As[lc * 4 + 1][lr + 32 * j] = pa[j].y;
            As[lc * 4 + 2][lr + 32 * j] = pa[j].z;
            As[lc * 4 + 3][lr + 32 * j] = pa[j].w;
        }
#pragma unroll
        for (int j = 0; j < 2; j++) {
            Bs[lc * 4 + 0][lr + 32 * j] = pb[j].x;
            Bs[lc * 4 + 1][lr + 32 * j] = pb[j].y;
            Bs[lc * 4 + 2][lr + 32 * j] = pb[j].z;
            Bs[lc * 4 + 3][lr + 32 * j] = pb[j].w;
        }
        __syncthreads();
        if (kb + 32 < DD) {
#pragma unroll
            for (int j = 0; j < 4; j++)
                pa[j] = *(const float4*)(x + (size_t)(bt0 + lr + 32 * j) * DD + kb + 32 + lc * 4);
#pragma unroll
            for (int j = 0; j < 2; j++)
                pb[j] = *(const float4*)(W + (size_t)(e0 + lr + 32 * j) * wstride + kb + 32 + lc * 4);
        }
#pragma unroll
        for (int k = 0; k < 32; k++) {
            float4 av  = *(const float4*)&As[k][tm * 4];
            float4 bv0 = *(const float4*)&Bs[k][tn * 8];
            float4 bv1 = *(const float4*)&Bs[k][tn * 8 + 4];
            float a_[4] = {av.x, av.y, av.z, av.w};
            float b_[8] = {bv0.x, bv0.y, bv0.z, bv0.w, bv1.x, bv1.y, bv1.z, bv1.w};
#pragma unroll
            for (int mi = 0; mi < 4; mi++)
#pragma unroll
                for (int ni = 0; ni < 8; ni++)
                    acc[mi][ni] = fmaf(a_[mi], b_[ni], acc[mi][ni]);
        }
        __syncthreads();
    }

#pragma unroll
    for (int mi = 0; mi < 4; mi++) {
        const int row = bt0 + tm * 4 + mi;
        float o[8];
#pragma unroll
        for (int ni = 0; ni < 8; ni++) o[ni] = __fadd_rn(acc[mi][ni], bias_r[ni]);
        float4 s0 = {o[0], o[1], o[2], o[3]};
        float4 s1 = {o[4], o[5], o[6], o[7]};
        *(float4*)(dst + (size_t)row * DD + e0 + tn * 8)     = s0;
        *(float4*)(dst + (size_t)row * DD + e0 + tn * 8 + 4) = s1;
    }
}

// ===========================================================================
// Scan: ONE 1024-thread WG per batch (64 WGs). No cross-WG communication.
// Thread (h = tid>>9, e = tid&511) holds Wt[e, h*256 .. h*256+255]:
//   chunk 2h   (128 f32) -> arch VGPRs, chunk 2h+1 (128 f32) -> AGPRs.
//
// KEY FIX vs rounds 1-2: amdgpu_waves_per_eu(4,4). A 1024-thread WG maps to
// 16 waves = 4 waves/SIMD; with launch_bounds(1024,1) LLVM's allocator chased
// a higher-occupancy register budget (VGPR_Count=64) and scratch-spilled both
// weight arrays (FETCH 19-20 GB, scan 30 ms). Clamping waves/EU to exactly 4
// sets the unified budget to 2048/4 = 512 regs/wave, so 128v+128a+~70 working
// fits with no memory spill. (Inline-asm pins only constrain placement at one
// point — they do NOT prevent loop-body spills; the budget is the real lever.)
//
// Reduction tree replicates the verified kernel bit-for-bit:
// per-chunk (a0+a1)+(a2+a3), total (P0+P1)+(P2+P3).
// ===========================================================================
__global__ __launch_bounds__(1024)
__attribute__((amdgpu_waves_per_eu(4, 4)))
void scan_kernel(
    const float* __restrict__ tau_w,
    float* __restrict__ xp_sp,          // out base: xp in, spikes out (in-place)
    const float* __restrict__ mm,       // ws: m (B,T,D)
    const float* __restrict__ thrp,
    float* __restrict__ tau_out, float* __restrict__ v_out)
{
    __shared__ __align__(16) float tau_lds[DD];
    __shared__ float partial[DD];

    const int b   = blockIdx.x;
    const int tid = threadIdx.x;
    const int h   = tid >> 9;        // 0: chunks 0,1 (k 0..255); 1: chunks 2,3
    const int e   = tid & 511;
    const bool owner = (h == 0);     // waves 0..7

    // resident weights: chunk c0 = 2h -> VGPRs, chunk c1 = 2h+1 -> AGPRs
    float wv[128];   // Wt[e][(2h)*128 + k],   k = 0..127
    float wa[128];   // Wt[e][(2h+1)*128 + k], k = 0..127
    {
        const f4* r0 = (const f4*)(tau_w + (size_t)e * 1024 + 512 + (2 * h) * 128);
        const f4* r1 = (const f4*)(tau_w + (size_t)e * 1024 + 512 + (2 * h + 1) * 128);
#pragma unroll
        for (int j = 0; j < 32; j++) {
            f4 t = r0[j];
            wv[4 * j + 0] = t.x; wv[4 * j + 1] = t.y;
            wv[4 * j + 2] = t.z; wv[4 * j + 3] = t.w;
        }
#pragma unroll
        for (int j = 0; j < 32; j++) {
            f4 t = r1[j];
            wa[4 * j + 0] = t.x; wa[4 * j + 1] = t.y;
            wa[4 * j + 2] = t.z; wa[4 * j + 3] = t.w;
        }
    }
#pragma unroll
    for (int j = 0; j < 128; j++) asm volatile("" : "+v"(wv[j]));  // arch VGPR
#pragma unroll
    for (int j = 0; j < 128; j++) asm volatile("" : "+a"(wa[j]));  // AGPR

    if (tid < DD) tau_lds[tid] = 1.0f;

    const float thr = thrp[0];
    float v = 0.0f, tau_keep = 1.0f;
    const size_t baseio = (size_t)b * TT * DD + e;

    __syncthreads();

    for (int i = 0; i < TT; i++) {
        // prefetch step inputs (in flight during the dot)
        float xpv = 0.0f, mv = 0.0f;
        if (owner) {
            xpv = xp_sp[baseio + (size_t)i * DD];
            mv  = mm  [baseio + (size_t)i * DD];
        }

        // dot over this thread's 2 chunks; tau reads are wave-uniform ->
        // LDS broadcast, conflict-free.
        float q;
        {
            float p0, p1;
            {   // chunk 2h (VGPR weights)
                const f4* tl = (const f4*)&tau_lds[(2 * h) * 128];
                float a0 = 0.f, a1 = 0.f, a2 = 0.f, a3 = 0.f;
#pragma unroll
                for (int j = 0; j < 32; j++) {
                    f4 t4 = tl[j];
                    a0 = fmaf(wv[4 * j + 0], t4.x, a0);
                    a1 = fmaf(wv[4 * j + 1], t4.y, a1);
                    a2 = fmaf(wv[4 * j + 2], t4.z, a2);
                    a3 = fmaf(wv[4 * j + 3], t4.w, a3);
                }
                p0 = (a0 + a1) + (a2 + a3);
            }
            {   // chunk 2h+1 (AGPR weights)
                const f4* tl = (const f4*)&tau_lds[(2 * h + 1) * 128];
                float a0 = 0.f, a1 = 0.f, a2 = 0.f, a3 = 0.f;
#pragma unroll
                for (int j = 0; j < 32; j++) {
                    f4 t4 = tl[j];
                    a0 = fmaf(wa[4 * j + 0], t4.x, a0);
                    a1 = fmaf(wa[4 * j + 1], t4.y, a1);
                    a2 = fmaf(wa[4 * j + 2], t4.z, a2);
                    a3 = fmaf(wa[4 * j + 3], t4.w, a3);
                }
                p1 = (a0 + a1) + (a2 + a3);
            }
            q = p0 + p1;   // h=0: P0+P1 ; h=1: P2+P3
        }
        if (!owner) partial[e] = q;
        __syncthreads();   // B: partials visible; all tau reads of step i done

        float tau_n = 0.0f;
        if (owner) {
            float dotv = q + partial[e];          // (P0+P1)+(P2+P3) — exact tree
            float z    = __fadd_rn(xpv, dotv);
            float enz  = expf(-z);
            tau_n      = 1.0f / __fadd_rn(1.0f, enz);
            tau_lds[e] = tau_n;                   // publish FIRST
        }
        __syncthreads();   // A: tau for step i+1 visible

        // tail overlaps next step's dot (non-owner waves already computing)
        if (owner) {
            tau_keep    = tau_n;
            float tpe   = __fadd_rn(tau_n, 1e-6f);
            float alpha = expf(-1.0f / tpe);
            float vn = __fadd_rn(__fmul_rn(alpha, v),
                                 __fmul_rn(__fsub_rn(1.0f, alpha), mv));
            bool s = (vn >= thr);
            xp_sp[baseio + (size_t)i * DD] = s ? 1.0f : 0.0f;
            v = s ? 0.0f : vn;
        }
    }

    if (owner) {
        tau_out[b * DD + e] = tau_keep;
        v_out  [b * DD + e] = v;
    }
}

extern "C" void kernel_launch(void* const* d_in, const int* in_sizes, int n_in,
                              void* d_out, int out_size, void* d_ws, size_t ws_size,
                              hipStream_t stream) {
    (void)in_sizes; (void)n_in; (void)out_size; (void)ws_size;
    const float* x     = (const float*)d_in[0];
    const float* tau_w = (const float*)d_in[1];
    const float* tau_b = (const float*)d_in[2];
    const float* mem_w = (const float*)d_in[3];
    const float* mem_b = (const float*)d_in[4];
    const float* thr   = (const float*)d_in[5];
    float* out = (float*)d_out;

    float* mm = (float*)d_ws;

    gemm_kernel<<<dim3(512, 16), 256, 0, stream>>>(x, tau_w, tau_b, mem_w, mem_b,
                                                   out, mm);
    scan_kernel<<<64, 1024, 0, stream>>>(tau_w, out, mm, thr,
                                         out + (size_t)BT * DD,
                                         out + (size_t)BT * DD + (size_t)BB * DD);
}

// Round 4
// 3234.406 us; speedup vs baseline: 9.7512x; 9.7484x over previous
//
#include <hip/hip_runtime.h>

#define BB 64
#define TT 1024
#define DD 512
#define BT (BB*TT)

#define SENT 0xFFFFFFFFFFFFFFFFULL
#define TAUG_WORDS (2ULL * 64 * 4 * 192)   // parity x (b,p) x 192 u64 slots

typedef float f4 __attribute__((ext_vector_type(4)));

// ===========================================================================
// GEMM: C[bt, e'] = sum_d x[bt,d] * W[e',d] + bias[e']   (all f32)
// (unchanged — verified absmax 0.0)
// ===========================================================================
__global__ __launch_bounds__(256, 2) void gemm_kernel(
    const float* __restrict__ x, const float* __restrict__ tau_w,
    const float* __restrict__ tau_b, const float* __restrict__ mem_w,
    const float* __restrict__ mem_b, float* __restrict__ xp, float* __restrict__ mm)
{
    __shared__ float As[32][132];
    __shared__ float Bs[32][68];

    const int tid  = threadIdx.x;
    const int bt0  = blockIdx.x * 128;
    const bool isxp = (blockIdx.y < 8);
    const float* W       = isxp ? tau_w : mem_w;
    const int    wstride = isxp ? 1024 : 512;
    const int    e0      = isxp ? blockIdx.y * 64 : blockIdx.y * 64 - 512;
    const float* bias    = isxp ? tau_b : mem_b;
    float*       dst     = isxp ? xp : mm;

    const int tm = tid & 31, tn = tid >> 5;
    const int lr = tid >> 3, lc = tid & 7;

    float bias_r[8];
#pragma unroll
    for (int ni = 0; ni < 8; ni++) bias_r[ni] = bias[e0 + tn * 8 + ni];

    float acc[4][8] = {};
    float4 pa[4], pb[2];

#pragma unroll
    for (int j = 0; j < 4; j++)
        pa[j] = *(const float4*)(x + (size_t)(bt0 + lr + 32 * j) * DD + lc * 4);
#pragma unroll
    for (int j = 0; j < 2; j++)
        pb[j] = *(const float4*)(W + (size_t)(e0 + lr + 32 * j) * wstride + lc * 4);

    for (int kb = 0; kb < DD; kb += 32) {
#pragma unroll
        for (int j = 0; j < 4; j++) {
            As[lc * 4 + 0][lr + 32 * j] = pa[j].x;
            As[lc * 4 + 1][lr + 32 * j] = pa[j].y;
            As[lc * 4 + 2][lr + 32 * j] = pa[j].z;
            As[lc * 4 + 3][lr + 32 * j] = pa[j].w;
        }
#pragma unroll
        for (int j = 0; j < 2; j++) {
            Bs[lc * 4 + 0][lr + 32 * j] = pb[j].x;
            Bs[lc * 4 + 1][lr + 32 * j] = pb[j].y;
            Bs[lc * 4 + 2][lr + 32 * j] = pb[j].z;
            Bs[lc * 4 + 3][lr + 32 * j] = pb[j].w;
        }
        __syncthreads();
        if (kb + 32 < DD) {
#pragma unroll
            for (int j = 0; j < 4; j++)
                pa[j] = *(const float4*)(x + (size_t)(bt0 + lr + 32 * j) * DD + kb + 32 + lc * 4);
#pragma unroll
            for (int j = 0; j < 2; j++)
                pb[j] = *(const float4*)(W + (size_t)(e0 + lr + 32 * j) * wstride + kb + 32 + lc * 4);
        }
#pragma unroll
        for (int k = 0; k < 32; k++) {
            float4 av  = *(const float4*)&As[k][tm * 4];
            float4 bv0 = *(const float4*)&Bs[k][tn * 8];
            float4 bv1 = *(const float4*)&Bs[k][tn * 8 + 4];
            float a_[4] = {av.x, av.y, av.z, av.w};
            float b_[8] = {bv0.x, bv0.y, bv0.z, bv0.w, bv1.x, bv1.y, bv1.z, bv1.w};
#pragma unroll
            for (int mi = 0; mi < 4; mi++)
#pragma unroll
                for (int ni = 0; ni < 8; ni++)
                    acc[mi][ni] = fmaf(a_[mi], b_[ni], acc[mi][ni]);
        }
        __syncthreads();
    }

#pragma unroll
    for (int mi = 0; mi < 4; mi++) {
        const int row = bt0 + tm * 4 + mi;
        float o[8];
#pragma unroll
        for (int ni = 0; ni < 8; ni++) o[ni] = __fadd_rn(acc[mi][ni], bias_r[ni]);
        float4 s0 = {o[0], o[1], o[2], o[3]};
        float4 s1 = {o[4], o[5], o[6], o[7]};
        *(float4*)(dst + (size_t)row * DD + e0 + tn * 8)     = s0;
        *(float4*)(dst + (size_t)row * DD + e0 + tn * 8 + 4) = s1;
    }
}

// ===========================================================================
// Scan: 4 WGs/batch, 256 WGs co-resident, 512 thr/WG, 128 weights/thread
// register-resident (PROVEN: VGPR=112, no spill). Protocol v2 vs round-0:
//   publish:  atomic STORE (was exchange)       — fire-and-forget, unchanged
//   poll:     atomic LOAD spin (was exchange RMW) — line reads broadcast to
//             the 8 lanes/64B-line, no exclusive ownership, no write-back;
//             round-0's RMW spin serialized 8 lanes/line at MALL (~4600cy/step)
//   re-arm:   relaxed atomic store of SENT after consume (for step i+2).
// Re-arm safety: barrier A drains vmcnt(0) (hipcc emits s_waitcnt vmcnt(0)
// before s_barrier), so rearm(X) is MALL-visible before this WG's publish(Y)
// issues; a peer only rewrites X after observing Y => rearm < rewrite. Depth-2
// parity + launch-time 0xFF memset unchanged.
// ===========================================================================
__global__ __launch_bounds__(512, 1) void scan_kernel(
    const float* __restrict__ tau_w,
    float* __restrict__ xp_sp,          // out base: xp in, spikes out
    const float* __restrict__ mm,       // ws: m (B,T,D)
    const float* __restrict__ thrp,
    float* __restrict__ tau_out, float* __restrict__ v_out,
    unsigned long long* __restrict__ taug64)  // ws: sentinel-filled
{
    __shared__ float tau_lds[DD];
    __shared__ float partial[4][128];

    const int wg = blockIdx.x;
    const int b = wg >> 2, p = wg & 3;
    const int tid = threadIdx.x;
    const int w = tid >> 6, lane = tid & 63;
    const int c  = w & 3;                    // k-chunk
    const int le = ((w >> 2) << 6) + lane;   // 0..127
    const int ge = p * 128 + le;             // owned e

    // resident weights: Wt[ge][c*128 .. c*128+127] as 128 scalars
    float wv[128];
    {
        const float4* wrow = (const float4*)(tau_w + (size_t)ge * 1024 + 512 + c * 128);
#pragma unroll
        for (int j = 0; j < 32; j++) {
            float4 t = wrow[j];
            wv[4 * j + 0] = t.x; wv[4 * j + 1] = t.y;
            wv[4 * j + 2] = t.z; wv[4 * j + 3] = t.w;
        }
    }
#pragma unroll
    for (int j = 0; j < 128; j++) asm volatile("" : "+v"(wv[j]));  // keep live

    if (tid < DD) tau_lds[tid] = 1.0f;

    const float thr = thrp[0];
    const bool owner = (c == 0);             // waves 0 and 4
    float v = 0.0f, tau_keep = 1.0f;
    const size_t baseio = (size_t)b * TT * DD + ge;

    __syncthreads();

    for (int i = 0; i < TT; i++) {
        // prefetch step inputs (in flight during poll/dot)
        float xpv = 0.0f, mv = 0.0f;
        if (owner) {
            xpv = xp_sp[baseio + (size_t)i * DD];
            mv  = mm  [baseio + (size_t)i * DD];
        }

        if (i > 0 && tid < 192) {
            // LOAD-poll (read-only spin at MALL), then re-arm with a plain
            // relaxed store for this slot's next use at step i+2.
            const int s = tid >> 6, j = tid & 63;
            const int qsrc = (p + 1 + s) & 3;
            unsigned long long* slot =
                &taug64[(size_t)(i & 1) * (64 * 4 * 192) +
                        (size_t)(b * 4 + p) * 192 + s * 64 + j];
            unsigned long long pk;
            do {
                pk = __hip_atomic_load(slot, __ATOMIC_RELAXED,
                                       __HIP_MEMORY_SCOPE_AGENT);
            } while (pk == SENT);
            __hip_atomic_store(slot, SENT, __ATOMIC_RELAXED,
                               __HIP_MEMORY_SCOPE_AGENT);   // re-arm for i+2
            const int e0 = qsrc * 128 + 2 * j;
            tau_lds[e0]     = __uint_as_float((unsigned int)(pk & 0xFFFFFFFFu));
            tau_lds[e0 + 1] = __uint_as_float((unsigned int)(pk >> 32));
        }
        __syncthreads();   // A: gathered remote tau + prev owner tau visible
                           //    (also drains re-arm stores to MALL)

        float a0 = 0.f, a1 = 0.f, a2 = 0.f, a3 = 0.f;
        {
            const f4* tl = (const f4*)&tau_lds[c * 128];
#pragma unroll
            for (int j = 0; j < 32; j++) {
                f4 t4 = tl[j];                // wave-uniform addr -> broadcast
                a0 = fmaf(wv[4 * j + 0], t4.x, a0);
                a1 = fmaf(wv[4 * j + 1], t4.y, a1);
                a2 = fmaf(wv[4 * j + 2], t4.z, a2);
                a3 = fmaf(wv[4 * j + 3], t4.w, a3);
            }
        }
        partial[c][le] = (a0 + a1) + (a2 + a3);
        __syncthreads();   // B: partials complete; all dot reads of tau_lds done

        if (owner) {
            float dotv = (partial[0][le] + partial[1][le]) +
                         (partial[2][le] + partial[3][le]);
            float z     = __fadd_rn(xpv, dotv);
            float enz   = expf(-z);
            float tau_n = 1.0f / __fadd_rn(1.0f, enz);
            tau_keep = tau_n;

            // publish FIRST (cross-WG critical path), then local math
            tau_lds[ge] = tau_n;
            if (i < TT - 1) {
                float pf = __shfl_xor(tau_n, 1);
                if ((lane & 1) == 0) {
                    unsigned long long pk =
                        (unsigned long long)__float_as_uint(tau_n) |
                        ((unsigned long long)__float_as_uint(pf) << 32);
                    const int pl = le >> 1;
#pragma unroll
                    for (int s2 = 0; s2 < 3; s2++) {
                        const int q  = (p + 1 + s2) & 3;
                        const int sr = 2 - s2;          // (p - q - 1) & 3
                        __hip_atomic_store(
                            &taug64[(size_t)((i + 1) & 1) * (64 * 4 * 192) +
                                    (size_t)(b * 4 + q) * 192 + sr * 64 + pl],
                            pk, __ATOMIC_RELAXED, __HIP_MEMORY_SCOPE_AGENT);
                    }
                }
            }

            float tpe   = __fadd_rn(tau_n, 1e-6f);
            float alpha = expf(-1.0f / tpe);
            float vn = __fadd_rn(__fmul_rn(alpha, v),
                                 __fmul_rn(__fsub_rn(1.0f, alpha), mv));
            bool s = (vn >= thr);
            xp_sp[baseio + (size_t)i * DD] = s ? 1.0f : 0.0f;
            v = s ? 0.0f : vn;
        }
        // no barrier here: next iteration's gather only touches remote
        // tau_lds regions after barrier A; partial reuse guarded by A as well.
    }

    if (owner) {
        tau_out[b * DD + ge] = tau_keep;
        v_out  [b * DD + ge] = v;
    }
}

extern "C" void kernel_launch(void* const* d_in, const int* in_sizes, int n_in,
                              void* d_out, int out_size, void* d_ws, size_t ws_size,
                              hipStream_t stream) {
    (void)in_sizes; (void)n_in; (void)out_size; (void)ws_size;
    const float* x     = (const float*)d_in[0];
    const float* tau_w = (const float*)d_in[1];
    const float* tau_b = (const float*)d_in[2];
    const float* mem_w = (const float*)d_in[3];
    const float* mem_b = (const float*)d_in[4];
    const float* thr   = (const float*)d_in[5];
    float* out = (float*)d_out;

    float* mm                   = (float*)d_ws;
    unsigned long long* taug64  = (unsigned long long*)(mm + (size_t)BT * DD);

    // re-arm sentinels (harness poisons d_ws to 0xAA before each replay)
    hipMemsetAsync(taug64, 0xFF, TAUG_WORDS * sizeof(unsigned long long), stream);

    gemm_kernel<<<dim3(512, 16), 256, 0, stream>>>(x, tau_w, tau_b, mem_w, mem_b,
                                                   out, mm);
    scan_kernel<<<256, 512, 0, stream>>>(tau_w, out, mm, thr,
                                         out + (size_t)BT * DD,
                                         out + (size_t)BT * DD + (size_t)BB * DD,
                                         taug64);
}

// Round 5
// 3153.192 us; speedup vs baseline: 10.0024x; 1.0258x over previous
//
#include <hip/hip_runtime.h>

#define BB 64
#define TT 1024
#define DD 512
#define BT (BB*TT)

// tag-protocol mailbox: parity x (b,p) x 128 u64 slots = 512 KiB
#define TAUG_WORDS (2ULL * 64 * 4 * 128)

typedef float f4 __attribute__((ext_vector_type(4)));

// ===========================================================================
// GEMM: C[bt, e'] = sum_d x[bt,d] * W[e',d] + bias[e']   (all f32)
// (unchanged — verified absmax 0.0)
// ===========================================================================
__global__ __launch_bounds__(256, 2) void gemm_kernel(
    const float* __restrict__ x, const float* __restrict__ tau_w,
    const float* __restrict__ tau_b, const float* __restrict__ mem_w,
    const float* __restrict__ mem_b, float* __restrict__ xp, float* __restrict__ mm)
{
    __shared__ float As[32][132];
    __shared__ float Bs[32][68];

    const int tid  = threadIdx.x;
    const int bt0  = blockIdx.x * 128;
    const bool isxp = (blockIdx.y < 8);
    const float* W       = isxp ? tau_w : mem_w;
    const int    wstride = isxp ? 1024 : 512;
    const int    e0      = isxp ? blockIdx.y * 64 : blockIdx.y * 64 - 512;
    const float* bias    = isxp ? tau_b : mem_b;
    float*       dst     = isxp ? xp : mm;

    const int tm = tid & 31, tn = tid >> 5;
    const int lr = tid >> 3, lc = tid & 7;

    float bias_r[8];
#pragma unroll
    for (int ni = 0; ni < 8; ni++) bias_r[ni] = bias[e0 + tn * 8 + ni];

    float acc[4][8] = {};
    float4 pa[4], pb[2];

#pragma unroll
    for (int j = 0; j < 4; j++)
        pa[j] = *(const float4*)(x + (size_t)(bt0 + lr + 32 * j) * DD + lc * 4);
#pragma unroll
    for (int j = 0; j < 2; j++)
        pb[j] = *(const float4*)(W + (size_t)(e0 + lr + 32 * j) * wstride + lc * 4);

    for (int kb = 0; kb < DD; kb += 32) {
#pragma unroll
        for (int j = 0; j < 4; j++) {
            As[lc * 4 + 0][lr + 32 * j] = pa[j].x;
            As[lc * 4 + 1][lr + 32 * j] = pa[j].y;
            As[lc * 4 + 2][lr + 32 * j] = pa[j].z;
            As[lc * 4 + 3][lr + 32 * j] = pa[j].w;
        }
#pragma unroll
        for (int j = 0; j < 2; j++) {
            Bs[lc * 4 + 0][lr + 32 * j] = pb[j].x;
            Bs[lc * 4 + 1][lr + 32 * j] = pb[j].y;
            Bs[lc * 4 + 2][lr + 32 * j] = pb[j].z;
            Bs[lc * 4 + 3][lr + 32 * j] = pb[j].w;
        }
        __syncthreads();
        if (kb + 32 < DD) {
#pragma unroll
            for (int j = 0; j < 4; j++)
                pa[j] = *(const float4*)(x + (size_t)(bt0 + lr + 32 * j) * DD + kb + 32 + lc * 4);
#pragma unroll
            for (int j = 0; j < 2; j++)
                pb[j] = *(const float4*)(W + (size_t)(e0 + lr + 32 * j) * wstride + kb + 32 + lc * 4);
        }
#pragma unroll
        for (int k = 0; k < 32; k++) {
            float4 av  = *(const float4*)&As[k][tm * 4];
            float4 bv0 = *(const float4*)&Bs[k][tn * 8];
            float4 bv1 = *(const float4*)&Bs[k][tn * 8 + 4];
            float a_[4] = {av.x, av.y, av.z, av.w};
            float b_[8] = {bv0.x, bv0.y, bv0.z, bv0.w, bv1.x, bv1.y, bv1.z, bv1.w};
#pragma unroll
            for (int mi = 0; mi < 4; mi++)
#pragma unroll
                for (int ni = 0; ni < 8; ni++)
                    acc[mi][ni] = fmaf(a_[mi], b_[ni], acc[mi][ni]);
        }
        __syncthreads();
    }

#pragma unroll
    for (int mi = 0; mi < 4; mi++) {
        const int row = bt0 + tm * 4 + mi;
        float o[8];
#pragma unroll
        for (int ni = 0; ni < 8; ni++) o[ni] = __fadd_rn(acc[mi][ni], bias_r[ni]);
        float4 s0 = {o[0], o[1], o[2], o[3]};
        float4 s1 = {o[4], o[5], o[6], o[7]};
        *(float4*)(dst + (size_t)row * DD + e0 + tn * 8)     = s0;
        *(float4*)(dst + (size_t)row * DD + e0 + tn * 8 + 4) = s1;
    }
}

// ===========================================================================
// Scan v3: 4 WGs/batch, 512 thr/WG, 128 weights/thread register-resident
// (PROVEN: VGPR=112, no spill). Protocol v3 — TAG-IN-SLOT, PER-WAVE GATHER:
//   slot[parity][b][p][j]  (j=0..127, one per producer lane)
//   publish: owner lane stores u64 = (tau_bits<<32)|tag, tag = consuming step.
//            SINGLE copy, no shuffle, no per-consumer duplication, no re-arm.
//   gather:  each wave polls ONLY its own k-chunk's quarter (2 slots/lane,
//            both kept in flight), tag-checked, into its PRIVATE LDS scratch;
//            wave-local lgkmcnt ordering only — NO workgroup barrier gates the
//            polls. Each wave's dot starts the moment ITS producer published;
//            the max-over-peers skew overlaps the dot instead of serializing
//            in front of it (round-4's barrier A gated all dots on the
//            slowest of 3 peers). Waves sharing a chunk poll duplicately
//            (reads are shareable at MALL; independence > dedup).
//   margin:  depth-2 parity. Producer publishes tag t+1 only after its own
//            gather of tag t, which transitively requires every peer past its
//            gather of t-1 -> overwrite-after-consume, same margin as the
//            proven round-0/4 protocol. Tags 1..1023 never collide with the
//            0xAA ws poison; region memset to 0 at launch for replay safety.
// Barriers: B (partials -> owner), A2 (owner tau_lds write -> next-step local
// read). 2/step, unchanged count. Compute/reduction bitwise identical.
// ===========================================================================
__global__ __launch_bounds__(512, 1) void scan_kernel(
    const float* __restrict__ tau_w,
    float* __restrict__ xp_sp,          // out base: xp in, spikes out
    const float* __restrict__ mm,       // ws: m (B,T,D)
    const float* __restrict__ thrp,
    float* __restrict__ tau_out, float* __restrict__ v_out,
    unsigned long long* __restrict__ taug64)  // ws: zero-filled mailbox
{
    __shared__ __align__(16) float tau_lds[DD];
    __shared__ float partial[4][128];
    __shared__ __align__(16) float scratch[8][128];   // per-wave gather buffer

    const int wg = blockIdx.x;
    const int b = wg >> 2, p = wg & 3;
    const int tid = threadIdx.x;
    const int w = tid >> 6, lane = tid & 63;
    const int c  = w & 3;                    // k-chunk this wave dots
    const int le = ((w >> 2) << 6) + lane;   // 0..127
    const int ge = p * 128 + le;             // owned e row
    const bool remote = (c != p);

    // resident weights: Wt[ge][c*128 .. c*128+127] as 128 scalars
    float wv[128];
    {
        const float4* wrow = (const float4*)(tau_w + (size_t)ge * 1024 + 512 + c * 128);
#pragma unroll
        for (int j = 0; j < 32; j++) {
            float4 t = wrow[j];
            wv[4 * j + 0] = t.x; wv[4 * j + 1] = t.y;
            wv[4 * j + 2] = t.z; wv[4 * j + 3] = t.w;
        }
    }
#pragma unroll
    for (int j = 0; j < 128; j++) asm volatile("" : "+v"(wv[j]));  // keep live

    if (tid < DD) tau_lds[tid] = 1.0f;

    const float thr = thrp[0];
    const bool owner = (c == 0);             // waves 0 and 4
    float v = 0.0f, tau_keep = 1.0f;
    const size_t baseio = (size_t)b * TT * DD + ge;

    __syncthreads();

    for (int i = 0; i < TT; i++) {
        // prefetch step inputs (in flight during gather/dot)
        float xpv = 0.0f, mv = 0.0f;
        if (owner) {
            xpv = xp_sp[baseio + (size_t)i * DD];
            mv  = mm  [baseio + (size_t)i * DD];
        }

        // -------- per-wave independent gather (no WG barrier) --------
        const float* tsrc;
        if (i > 0 && remote) {
            const unsigned tg = (unsigned)i;
            unsigned long long* sA =
                &taug64[(size_t)(i & 1) * (64 * 4 * 128) +
                        (size_t)(b * 4 + c) * 128 + lane];
            unsigned long long* sB = sA + 64;
            unsigned long long pkA, pkB;
            do {   // both probes in flight per iteration; tag-checked
                pkA = __hip_atomic_load(sA, __ATOMIC_RELAXED,
                                        __HIP_MEMORY_SCOPE_AGENT);
                pkB = __hip_atomic_load(sB, __ATOMIC_RELAXED,
                                        __HIP_MEMORY_SCOPE_AGENT);
            } while ((unsigned)pkA != tg || (unsigned)pkB != tg);
            scratch[w][lane]      = __uint_as_float((unsigned)(pkA >> 32));
            scratch[w][lane + 64] = __uint_as_float((unsigned)(pkB >> 32));
            // wave-local write->read handoff: drain LDS writes, pin order
            asm volatile("s_waitcnt lgkmcnt(0)" ::: "memory");
            __builtin_amdgcn_sched_barrier(0);
            tsrc = &scratch[w][0];
        } else {
            tsrc = &tau_lds[c * 128];   // local quarter (or step-0 init 1.0)
        }

        float a0 = 0.f, a1 = 0.f, a2 = 0.f, a3 = 0.f;
        {
            const f4* tl = (const f4*)tsrc;
#pragma unroll
            for (int j = 0; j < 32; j++) {
                f4 t4 = tl[j];                // wave-uniform addr -> broadcast
                a0 = fmaf(wv[4 * j + 0], t4.x, a0);
                a1 = fmaf(wv[4 * j + 1], t4.y, a1);
                a2 = fmaf(wv[4 * j + 2], t4.z, a2);
                a3 = fmaf(wv[4 * j + 3], t4.w, a3);
            }
        }
        partial[c][le] = (a0 + a1) + (a2 + a3);
        __syncthreads();   // B: partials complete

        if (owner) {
            float dotv = (partial[0][le] + partial[1][le]) +
                         (partial[2][le] + partial[3][le]);
            float z     = __fadd_rn(xpv, dotv);
            float enz   = expf(-z);
            float tau_n = 1.0f / __fadd_rn(1.0f, enz);
            tau_keep = tau_n;

            // publish FIRST (cross-WG critical path): one 8B tagged store
            tau_lds[ge] = tau_n;
            if (i < TT - 1) {
                unsigned long long pk =
                    ((unsigned long long)__float_as_uint(tau_n) << 32) |
                    (unsigned long long)(unsigned)(i + 1);
                __hip_atomic_store(
                    &taug64[(size_t)((i + 1) & 1) * (64 * 4 * 128) +
                            (size_t)(b * 4 + p) * 128 + le],
                    pk, __ATOMIC_RELAXED, __HIP_MEMORY_SCOPE_AGENT);
            }

            float tpe   = __fadd_rn(tau_n, 1e-6f);
            float alpha = expf(-1.0f / tpe);
            float vn = __fadd_rn(__fmul_rn(alpha, v),
                                 __fmul_rn(__fsub_rn(1.0f, alpha), mv));
            bool s = (vn >= thr);
            xp_sp[baseio + (size_t)i * DD] = s ? 1.0f : 0.0f;
            v = s ? 0.0f : vn;
        }
        __syncthreads();   // A2: owner's tau_lds write visible to local waves
    }

    if (owner) {
        tau_out[b * DD + ge] = tau_keep;
        v_out  [b * DD + ge] = v;
    }
}

extern "C" void kernel_launch(void* const* d_in, const int* in_sizes, int n_in,
                              void* d_out, int out_size, void* d_ws, size_t ws_size,
                              hipStream_t stream) {
    (void)in_sizes; (void)n_in; (void)out_size; (void)ws_size;
    const float* x     = (const float*)d_in[0];
    const float* tau_w = (const float*)d_in[1];
    const float* tau_b = (const float*)d_in[2];
    const float* mem_w = (const float*)d_in[3];
    const float* mem_b = (const float*)d_in[4];
    const float* thr   = (const float*)d_in[5];
    float* out = (float*)d_out;

    float* mm                   = (float*)d_ws;
    unsigned long long* taug64  = (unsigned long long*)(mm + (size_t)BT * DD);

    // clear mailbox tags (0 is never a valid tag; guards replay staleness)
    hipMemsetAsync(taug64, 0x00, TAUG_WORDS * sizeof(unsigned long long), stream);

    gemm_kernel<<<dim3(512, 16), 256, 0, stream>>>(x, tau_w, tau_b, mem_w, mem_b,
                                                   out, mm);
    scan_kernel<<<256, 512, 0, stream>>>(tau_w, out, mm, thr,
                                         out + (size_t)BT * DD,
                                         out + (size_t)BT * DD + (size_t)BB * DD,
                                         taug64);
}

// Round 7
// 2673.984 us; speedup vs baseline: 11.7949x; 1.1792x over previous
//
#include <hip/hip_runtime.h>

#define BB 64
#define TT 1024
#define DD 512
#define BT (BB*TT)

// partial-exchange mailbox: parity x b x q(4) x cidx(3) x j(128) u32 slots
// = 196608 u32 = 768 KiB — byte-identical footprint to the round-0-proven
// allocation (2*64*4*192 u64). Sentinel = 0xFFFFFFFF (NaN pattern; partials
// are finite sums of finite products — unreachable).
#define TAUG_SLOTS (2ULL * 64 * 4 * 3 * 128)
#define SENT32 0xFFFFFFFFu

typedef float f4 __attribute__((ext_vector_type(4)));

// ===========================================================================
// GEMM: C[bt, e'] = sum_d x[bt,d] * W[e',d] + bias[e']   (all f32)
// (unchanged — verified absmax 0.0)
// ===========================================================================
__global__ __launch_bounds__(256, 2) void gemm_kernel(
    const float* __restrict__ x, const float* __restrict__ tau_w,
    const float* __restrict__ tau_b, const float* __restrict__ mem_w,
    const float* __restrict__ mem_b, float* __restrict__ xp, float* __restrict__ mm)
{
    __shared__ float As[32][132];
    __shared__ float Bs[32][68];

    const int tid  = threadIdx.x;
    const int bt0  = blockIdx.x * 128;
    const bool isxp = (blockIdx.y < 8);
    const float* W       = isxp ? tau_w : mem_w;
    const int    wstride = isxp ? 1024 : 512;
    const int    e0      = isxp ? blockIdx.y * 64 : blockIdx.y * 64 - 512;
    const float* bias    = isxp ? tau_b : mem_b;
    float*       dst     = isxp ? xp : mm;

    const int tm = tid & 31, tn = tid >> 5;
    const int lr = tid >> 3, lc = tid & 7;

    float bias_r[8];
#pragma unroll
    for (int ni = 0; ni < 8; ni++) bias_r[ni] = bias[e0 + tn * 8 + ni];

    float acc[4][8] = {};
    float4 pa[4], pb[2];

#pragma unroll
    for (int j = 0; j < 4; j++)
        pa[j] = *(const float4*)(x + (size_t)(bt0 + lr + 32 * j) * DD + lc * 4);
#pragma unroll
    for (int j = 0; j < 2; j++)
        pb[j] = *(const float4*)(W + (size_t)(e0 + lr + 32 * j) * wstride + lc * 4);

    for (int kb = 0; kb < DD; kb += 32) {
#pragma unroll
        for (int j = 0; j < 4; j++) {
            As[lc * 4 + 0][lr + 32 * j] = pa[j].x;
            As[lc * 4 + 1][lr + 32 * j] = pa[j].y;
            As[lc * 4 + 2][lr + 32 * j] = pa[j].z;
            As[lc * 4 + 3][lr + 32 * j] = pa[j].w;
        }
#pragma unroll
        for (int j = 0; j < 2; j++) {
            Bs[lc * 4 + 0][lr + 32 * j] = pb[j].x;
            Bs[lc * 4 + 1][lr + 32 * j] = pb[j].y;
            Bs[lc * 4 + 2][lr + 32 * j] = pb[j].z;
            Bs[lc * 4 + 3][lr + 32 * j] = pb[j].w;
        }
        __syncthreads();
        if (kb + 32 < DD) {
#pragma unroll
            for (int j = 0; j < 4; j++)
                pa[j] = *(const float4*)(x + (size_t)(bt0 + lr + 32 * j) * DD + kb + 32 + lc * 4);
#pragma unroll
            for (int j = 0; j < 2; j++)
                pb[j] = *(const float4*)(W + (size_t)(e0 + lr + 32 * j) * wstride + kb + 32 + lc * 4);
        }
#pragma unroll
        for (int k = 0; k < 32; k++) {
            float4 av  = *(const float4*)&As[k][tm * 4];
            float4 bv0 = *(const float4*)&Bs[k][tn * 8];
            float4 bv1 = *(const float4*)&Bs[k][tn * 8 + 4];
            float a_[4] = {av.x, av.y, av.z, av.w};
            float b_[8] = {bv0.x, bv0.y, bv0.z, bv0.w, bv1.x, bv1.y, bv1.z, bv1.w};
#pragma unroll
            for (int mi = 0; mi < 4; mi++)
#pragma unroll
                for (int ni = 0; ni < 8; ni++)
                    acc[mi][ni] = fmaf(a_[mi], b_[ni], acc[mi][ni]);
        }
        __syncthreads();
    }

#pragma unroll
    for (int mi = 0; mi < 4; mi++) {
        const int row = bt0 + tm * 4 + mi;
        float o[8];
#pragma unroll
        for (int ni = 0; ni < 8; ni++) o[ni] = __fadd_rn(acc[mi][ni], bias_r[ni]);
        float4 s0 = {o[0], o[1], o[2], o[3]};
        float4 s1 = {o[4], o[5], o[6], o[7]};
        *(float4*)(dst + (size_t)row * DD + e0 + tn * 8)     = s0;
        *(float4*)(dst + (size_t)row * DD + e0 + tn * 8 + 4) = s1;
    }
}

// ===========================================================================
// Scan v4b — PARTIAL-EXCHANGE + XCD COLOCATION, sentinel-u32 mailbox.
//
// WG (b,p) owns e-quarter p AND k-chunk p. Its tau chunk is produced LOCALLY,
// so the dot needs NO remote input: thread t computes the chunk-p partial for
// row e=t (128 resident weight regs — proven layout, VGPR=112, no spill).
// What crosses WGs is the dot RESULT (1 f32 per (e, src-chunk)):
//   producer: thread t (q = t>>7 != p) stores partial bits, fire-and-forget.
//   consumer: owner thread t (q == p) polls its 3 slots until != SENT32,
//             re-arms them to SENT32 (for step i+2 — round-4-proven
//             mechanism: rearm < our-publish < peer-observes < peer-rewrite,
//             via the vmcnt(0) drain at the end-of-step barrier), sums with
//             its in-register local partial as (P0+P1)+(P2+P3) — exact tree —
//             then sigmoid, tau -> ping-pong LDS buf, v/spike tail.
// ONE barrier/step. Post-hop serial path is only: detect + sum3 + sigmoid.
// XCD colocation: bid = b + 64p  =>  bid%8 == b%8 for all 4 WGs of a batch;
// round-robin bid->XCD places them on ONE XCD: the mailbox slice stays in
// that XCD's L2 (hop ~300cy vs MALL ~900cy). Wrong placement = perf-neutral.
// Depth-2 parity margin (liveness, re-audited): P_c overwrites slot S only
// from step i+2, which requires P_c's end-of-step-i+1 barrier -> P_c's owner
// polled step-i+1 msgs -> needed P_q's step-i+1 publishes -> P_q passed its
// end-of-step-i barrier -> P_q's owner had consumed S. Sentinel 0xFFFFFFFF
// doubles as the replay guard (launch memset 0xFF over the 0xAA ws poison).
// ===========================================================================
__global__ __launch_bounds__(512, 1) void scan_kernel(
    const float* __restrict__ tau_w,
    float* __restrict__ xp_sp,          // out base: xp in, spikes out
    const float* __restrict__ mm,       // ws: m (B,T,D)
    const float* __restrict__ thrp,
    float* __restrict__ tau_out, float* __restrict__ v_out,
    unsigned int* __restrict__ taug32)  // ws: sentinel-filled mailbox
{
    __shared__ __align__(16) float tau_buf[2][128];

    const int bid = blockIdx.x;
    const int b = bid & 63, p = bid >> 6;    // XCD colocation remap
    const int t = threadIdx.x;               // == global weight row e
    const int q = t >> 7;                    // e-quarter of this row
    const int j = t & 127;
    const bool owner = (q == p);             // waves 2p, 2p+1

    // resident weights: Wt[e=t][p*128 .. p*128+127] as 128 scalars
    float wv[128];
    {
        const float4* wrow = (const float4*)(tau_w + (size_t)t * 1024 + 512 + p * 128);
#pragma unroll
        for (int jj = 0; jj < 32; jj++) {
            float4 w4 = wrow[jj];
            wv[4 * jj + 0] = w4.x; wv[4 * jj + 1] = w4.y;
            wv[4 * jj + 2] = w4.z; wv[4 * jj + 3] = w4.w;
        }
    }
#pragma unroll
    for (int jj = 0; jj < 128; jj++) asm volatile("" : "+v"(wv[jj]));  // keep live

    if (t < 128) tau_buf[0][t] = 1.0f;       // tau0 carry = 1.0 (chunk p)

    const float thr = thrp[0];
    float v = 0.0f, tau_keep = 1.0f;
    const size_t baseio = (size_t)b * TT * DD + t;

    __syncthreads();

    for (int i = 0; i < TT; i++) {
        // prefetch step inputs (in flight during the dot)
        float xpv = 0.0f, mv = 0.0f;
        if (owner) {
            xpv = xp_sp[baseio + (size_t)i * DD];
            mv  = mm  [baseio + (size_t)i * DD];
        }

        // local dot: chunk-p partial for row e=t. tau reads are wave-uniform
        // (identical for all 8 waves) -> LDS broadcast, conflict-free.
        float a0 = 0.f, a1 = 0.f, a2 = 0.f, a3 = 0.f;
        {
            const f4* tl = (const f4*)&tau_buf[i & 1][0];
#pragma unroll
            for (int jj = 0; jj < 32; jj++) {
                f4 t4 = tl[jj];
                a0 = fmaf(wv[4 * jj + 0], t4.x, a0);
                a1 = fmaf(wv[4 * jj + 1], t4.y, a1);
                a2 = fmaf(wv[4 * jj + 2], t4.z, a2);
                a3 = fmaf(wv[4 * jj + 3], t4.w, a3);
            }
        }
        const float part = (a0 + a1) + (a2 + a3);   // P_p[e=t], exact tree

        const size_t pb = (size_t)(((i & 1) * 64 + b) * 4);
        if (!owner) {
            // single fire-and-forget publish to e's owner WG
            const int cidx = (p < q) ? p : p - 1;
            __hip_atomic_store(&taug32[(pb + q) * 384 + (size_t)cidx * 128 + j],
                               __float_as_uint(part),
                               __ATOMIC_RELAXED, __HIP_MEMORY_SCOPE_AGENT);
        } else {
            // poll the 3 remote partials for row e=t (all kept in flight)
            unsigned int* s0 = &taug32[(pb + p) * 384 + j];
            unsigned int k0, k1, k2;
            do {
                k0 = __hip_atomic_load(s0,       __ATOMIC_RELAXED, __HIP_MEMORY_SCOPE_AGENT);
                k1 = __hip_atomic_load(s0 + 128, __ATOMIC_RELAXED, __HIP_MEMORY_SCOPE_AGENT);
                k2 = __hip_atomic_load(s0 + 256, __ATOMIC_RELAXED, __HIP_MEMORY_SCOPE_AGENT);
            } while (k0 == SENT32 || k1 == SENT32 || k2 == SENT32);
            // re-arm for this slot's next use at step i+2 (drained at barrier)
            __hip_atomic_store(s0,       SENT32, __ATOMIC_RELAXED, __HIP_MEMORY_SCOPE_AGENT);
            __hip_atomic_store(s0 + 128, SENT32, __ATOMIC_RELAXED, __HIP_MEMORY_SCOPE_AGENT);
            __hip_atomic_store(s0 + 256, SENT32, __ATOMIC_RELAXED, __HIP_MEMORY_SCOPE_AGENT);
            const float r0 = __uint_as_float(k0);
            const float r1 = __uint_as_float(k1);
            const float r2 = __uint_as_float(k2);
            // cidx<->chunk: c<p at cidx=c, c>p at cidx=c-1; own chunk = part
            const float pp0 = (p == 0) ? part : r0;
            const float pp1 = (p == 0) ? r0 : ((p == 1) ? part : r1);
            const float pp2 = (p <= 1) ? r1 : ((p == 2) ? part : r2);
            const float pp3 = (p == 3) ? part : r2;

            float dotv  = (pp0 + pp1) + (pp2 + pp3);   // (P0+P1)+(P2+P3) exact
            float z     = __fadd_rn(xpv, dotv);
            float enz   = expf(-z);
            float tau_n = 1.0f / __fadd_rn(1.0f, enz);
            tau_keep = tau_n;
            tau_buf[(i + 1) & 1][j] = tau_n;   // local publish FIRST

            float tpe   = __fadd_rn(tau_n, 1e-6f);
            float alpha = expf(-1.0f / tpe);
            float vn = __fadd_rn(__fmul_rn(alpha, v),
                                 __fmul_rn(__fsub_rn(1.0f, alpha), mv));
            bool s = (vn >= thr);
            xp_sp[baseio + (size_t)i * DD] = s ? 1.0f : 0.0f;
            v = s ? 0.0f : vn;
        }
        __syncthreads();   // owner's tau_buf[(i+1)&1] -> step i+1 dot reads;
                           // drains publishes + re-arms (vmcnt(0) pre-barrier)
    }

    if (owner) {
        tau_out[b * DD + t] = tau_keep;
        v_out  [b * DD + t] = v;
    }
}

extern "C" void kernel_launch(void* const* d_in, const int* in_sizes, int n_in,
                              void* d_out, int out_size, void* d_ws, size_t ws_size,
                              hipStream_t stream) {
    (void)in_sizes; (void)n_in; (void)out_size; (void)ws_size;
    const float* x     = (const float*)d_in[0];
    const float* tau_w = (const float*)d_in[1];
    const float* tau_b = (const float*)d_in[2];
    const float* mem_w = (const float*)d_in[3];
    const float* mem_b = (const float*)d_in[4];
    const float* thr   = (const float*)d_in[5];
    float* out = (float*)d_out;

    float* mm              = (float*)d_ws;
    unsigned int* taug32   = (unsigned int*)(mm + (size_t)BT * DD);

    // re-arm sentinels (harness poisons d_ws to 0xAA before each replay);
    // 768 KiB — identical workspace footprint to the round-0-proven kernel.
    hipMemsetAsync(taug32, 0xFF, TAUG_SLOTS * sizeof(unsigned int), stream);

    gemm_kernel<<<dim3(512, 16), 256, 0, stream>>>(x, tau_w, tau_b, mem_w, mem_b,
                                                   out, mm);
    scan_kernel<<<256, 512, 0, stream>>>(tau_w, out, mm, thr,
                                         out + (size_t)BT * DD,
                                         out + (size_t)BT * DD + (size_t)BB * DD,
                                         taug32);
}